// Round 15
// baseline (99.063 us; speedup 1.0000x reference)
//
#include <hip/hip_runtime.h>

#define NT 2000000
#define NE 20000
#define NT4 (NT / 4)          // 500000, exact
#define K1_BLOCKS 1024
#define K1_WAVES (K1_BLOCKS * 4)   // 4096 -> 4.88 events/wave
#define K2_BLOCKS ((NE + 63) / 64) // 313
#define NSEG 65

using half8  = __attribute__((ext_vector_type(8))) _Float16;
using f32x4  = __attribute__((ext_vector_type(4))) float;
using fvec4  = __attribute__((ext_vector_type(4))) float;

// 8 consecutive f32 -> f16x8
__device__ __forceinline__ half8 load_h8(const float* __restrict__ p) {
    fvec4 a = *(const fvec4*)p;
    fvec4 b = *(const fvec4*)(p + 4);
    half8 r;
#pragma unroll
    for (int e = 0; e < 4; e++) {
        r[e]     = (_Float16)a[e];
        r[e + 4] = (_Float16)b[e];
    }
    return r;
}

// ---------------- K_PRE: piecewise-linear table for phi1 ----------------
// phi1(v) is piecewise-linear in the SCALAR v with 64 knees t_k = -b0_k/w0_k.
// Segment s (= #knees strictly below v): h2_j = relu(a[s][j]*v + c[s][j]).
// active_k(s): w0>0-style -> s > rank_k; w0<0-style -> s <= rank_k.
// w0==0: b0>0 -> always active (t=-INF, pos-style); else never (t=+INF).
// Self-consistent with k1's ballot-count because seg uses the same compare.
__global__ __launch_bounds__(64) void k_pre(
    const float* __restrict__ w0, const float* __restrict__ b0,
    const float* __restrict__ w1, const float* __restrict__ b1,
    float* __restrict__ sorted_t, float2* __restrict__ tab) {
    __shared__ float tS[64], w0S[64], b0S[64];
    __shared__ int rankS[64], styleS[64];
    const int k = threadIdx.x;
    const float w = w0[k], b = b0[k];
    float t; int style;
    if (w != 0.f) { t = -b / w; style = (w > 0.f) ? 1 : 0; }
    else          { t = (b > 0.f) ? -INFINITY : INFINITY; style = 1; }
    tS[k] = t; w0S[k] = w; b0S[k] = b; styleS[k] = style;
    __syncthreads();
    int rank = 0;
    for (int i = 0; i < 64; i++) {
        const float ti = tS[i];
        rank += (ti < t || (ti == t && i < k)) ? 1 : 0;
    }
    rankS[k] = rank;
    __syncthreads();
    if (blockIdx.x == 0) sorted_t[rank] = t;

    const int s = blockIdx.x;              // segment 0..64
    float a = 0.f, c = b1[k];              // thread k = output feature j
    for (int kk = 0; kk < 64; kk++) {
        const bool act = styleS[kk] ? (s > rankS[kk]) : (s <= rankS[kk]);
        if (act) {
            const float wjk = w1[k * 64 + kk];
            a = fmaf(wjk, w0S[kk], a);
            c = fmaf(wjk, b0S[kk], c);
        }
    }
    tab[s * 64 + k] = make_float2(a, c);
}

// ---------------- K0: event offsets via boundary scatter + zero s2/counter -------
__global__ __launch_bounds__(256) void k0_offsets(
    const int* __restrict__ seg, int* __restrict__ off, float* __restrict__ s2,
    int* __restrict__ counter) {
    if (blockIdx.x == 0) {
        if (threadIdx.x < 64) s2[threadIdx.x] = 0.f;
        if (threadIdx.x == 64) *counter = 0;
    }
    const int g = blockIdx.x * 256 + threadIdx.x;
    if (g >= NT4) return;
    const int idx4 = g * 4;
    const int4 s = *(const int4*)(seg + idx4);
    int prev = (g == 0) ? -1 : seg[idx4 - 1];
    int vals[4] = {s.x, s.y, s.z, s.w};
#pragma unroll
    for (int k = 0; k < 4; k++) {
        const int cur = vals[k];
        if (cur != prev) {
            for (int e = prev + 1; e <= cur; ++e) off[e] = idx4 + k;
        }
        prev = cur;
    }
    if (idx4 + 3 == NT - 1) {
        for (int e = prev + 1; e <= NE; ++e) off[e] = NT;
    }
}

// ---------------- K1: phi1 via piecewise-linear table + per-event sum ------------
// r14 post-mortem: MFMA formulation capped at 42us by AGPR-pinned residency
// (~2.5 waves/SIMD) x serial MFMA chains. This kernel has NO MFMA: per
// particle = readlane-broadcast v, seg = popcount(ballot(v > knee_lane)),
// one ds_read_b64 of (a,c), fma+max+add. Lane l = feature l, direct store.
__global__ __launch_bounds__(256) void k1_phi1(
    const float* __restrict__ values, const int* __restrict__ off,
    const float* __restrict__ sorted_t, const float2* __restrict__ gtab,
    float* __restrict__ ev) {
    __shared__ __align__(16) float2 tab[NSEG * 64];   // 33280 B
    const int tid = threadIdx.x;
    const int w = tid >> 6, l = tid & 63;

    for (int idx = tid; idx < NSEG * 64; idx += 256) tab[idx] = gtab[idx];
    const float t_l = sorted_t[l];
    __syncthreads();

    const int wid = blockIdx.x * 4 + w;
    for (int e = wid; e < NE; e += K1_WAVES) {
        const int ps = off[e], pe = off[e + 1];
        float sjA = 0.f, sjB = 0.f;                  // 2 chains break add-dep
        for (int base = ps; base < pe; base += 64) {
            const int cnt = pe - base;               // uniform; loop caps at 64
            const float v_l = (base + l < pe) ? values[base + l] : 0.f;
#pragma unroll
            for (int i = 0; i < 64; i += 2) {
                if (i >= cnt) break;                 // uniform break
                {
                    const float vs = __shfl(v_l, i);         // v_readlane
                    const int sg = (int)__popcll(__ballot(vs > t_l));
                    const float2 ac = tab[sg * 64 + l];
                    sjA += fmaxf(fmaf(ac.x, vs, ac.y), 0.f);
                }
                if (i + 1 < cnt) {
                    const float vs = __shfl(v_l, i + 1);
                    const int sg = (int)__popcll(__ballot(vs > t_l));
                    const float2 ac = tab[sg * 64 + l];
                    sjB += fmaxf(fmaf(ac.x, vs, ac.y), 0.f);
                }
            }
        }
        ev[(size_t)e * 64 + l] = sjA + sjB;          // one wave owns event e
    }
}

// ------- K2: rho1+o1+phi2 (5 fused layers, f16 single) + event-sum + k3 tail -----
// (byte-identical to r14: 64-event/wave, 313 blocks, last-block rho2 tail)
__global__ __launch_bounds__(64) void k2_events(
    const float* __restrict__ ev,
    const float* __restrict__ W0, const float* __restrict__ B0,
    const float* __restrict__ W1, const float* __restrict__ B1,
    const float* __restrict__ W2, const float* __restrict__ B2,
    const float* __restrict__ W3, const float* __restrict__ B3,
    const float* __restrict__ W4, const float* __restrict__ B4,
    float* __restrict__ s2, int* __restrict__ counter,
    const float* __restrict__ R0, const float* __restrict__ Rb0,
    const float* __restrict__ R1, const float* __restrict__ Rb1,
    const float* __restrict__ OW, const float* __restrict__ OB,
    float* __restrict__ out) {
    __shared__ __align__(16) _Float16 xt[64 * 72];   // [e][k], stride 72
    const int l   = threadIdx.x;
    const int l15 = l & 15;
    const int l4  = l >> 4;
    const int ebase = blockIdx.x * 64;

    const float* Ws[5] = {W0, W1, W2, W3, W4};
    const float* Bs[5] = {B0, B1, B2, B3, B4};

    half8 A[4][2];
#pragma unroll
    for (int pf = 0; pf < 4; pf++) {
        const int e = ebase + pf * 16 + l15;
#pragma unroll
        for (int kf = 0; kf < 2; kf++) {
            half8 a;
            if (e < NE) {
                a = load_h8(ev + (size_t)e * 64 + kf * 32 + l4 * 8);
            } else {
#pragma unroll
                for (int e2 = 0; e2 < 8; e2++) a[e2] = (_Float16)0.f;
            }
            A[pf][kf] = a;
        }
    }

#pragma unroll
    for (int L = 0; L < 5; L++) {
        half8 Bh[2][4];
#pragma unroll
        for (int kf = 0; kf < 2; kf++)
#pragma unroll
            for (int jf = 0; jf < 4; jf++)
                Bh[kf][jf] = load_h8(Ws[L] + (jf * 16 + l15) * 64 +
                                     kf * 32 + l4 * 8);

        f32x4 acc[4][4];
#pragma unroll
        for (int jf = 0; jf < 4; jf++) {
            const float bj = Bs[L][jf * 16 + l15];
#pragma unroll
            for (int pf = 0; pf < 4; pf++)
#pragma unroll
                for (int r = 0; r < 4; r++) acc[pf][jf][r] = bj;
        }
#pragma unroll
        for (int kf = 0; kf < 2; kf++)
#pragma unroll
            for (int pf = 0; pf < 4; pf++)
#pragma unroll
                for (int jf = 0; jf < 4; jf++)
                    acc[pf][jf] = __builtin_amdgcn_mfma_f32_16x16x32_f16(
                        A[pf][kf], Bh[kf][jf], acc[pf][jf], 0, 0, 0);

        if (L < 4) {
#pragma unroll
            for (int pf = 0; pf < 4; pf++)
#pragma unroll
                for (int jf = 0; jf < 4; jf++) {
                    const int j = jf * 16 + l15;
#pragma unroll
                    for (int r = 0; r < 4; r++)
                        xt[(pf * 16 + l4 * 4 + r) * 72 + j] =
                            (_Float16)fmaxf(acc[pf][jf][r], 0.f);
                }
#pragma unroll
            for (int pf = 0; pf < 4; pf++)
#pragma unroll
                for (int kf = 0; kf < 2; kf++)
                    A[pf][kf] = *(const half8*)(xt + (pf * 16 + l15) * 72 +
                                                kf * 32 + l4 * 8);
        } else {
            float sj[4];
#pragma unroll
            for (int jf = 0; jf < 4; jf++) {
                float s = 0.f;
#pragma unroll
                for (int pf = 0; pf < 4; pf++)
#pragma unroll
                    for (int r = 0; r < 4; r++) {
                        const int e = ebase + pf * 16 + l4 * 4 + r;
                        float v = fmaxf(acc[pf][jf][r], 0.f);
                        s += (e < NE) ? v : 0.f;
                    }
                s += __shfl_xor(s, 16);
                s += __shfl_xor(s, 32);
                sj[jf] = s;
            }
            float v = (l4 == 0) ? sj[0] : (l4 == 1) ? sj[1]
                    : (l4 == 2) ? sj[2] : sj[3];
            atomicAdd(s2 + l, v);
        }
    }

    // ---- fused rho2 + output + log_softmax: last block to finish does it ----
    __shared__ int is_last;
    __threadfence();
    if (l == 0) {
        const int c = atomicAdd(counter, 1);
        is_last = (c == (int)gridDim.x - 1);
    }
    __syncthreads();
    if (!is_last) return;

    __shared__ __align__(16) float xb[64];
    __shared__ __align__(16) float yb[64];
    __shared__ float ob[10];

    xb[l] = atomicAdd(s2 + l, 0.f);   // coherent read (fence+counter ordered)
    __syncthreads();

    float a0 = Rb0[l];
#pragma unroll
    for (int k = 0; k < 16; k++) {
        fvec4 wv = *(const fvec4*)(R0 + l * 64 + k * 4);
        fvec4 xv = *(const fvec4*)(xb + k * 4);
        a0 += wv[0] * xv[0] + wv[1] * xv[1] + wv[2] * xv[2] + wv[3] * xv[3];
    }
    yb[l] = fmaxf(a0, 0.f);
    __syncthreads();

    float b_ = Rb1[l];
#pragma unroll
    for (int k = 0; k < 16; k++) {
        fvec4 wv = *(const fvec4*)(R1 + l * 64 + k * 4);
        fvec4 xv = *(const fvec4*)(yb + k * 4);
        b_ += wv[0] * xv[0] + wv[1] * xv[1] + wv[2] * xv[2] + wv[3] * xv[3];
    }
    __syncthreads();
    xb[l] = fmaxf(b_, 0.f);
    __syncthreads();

    if (l < 10) {
        float o = OB[l];
#pragma unroll
        for (int k = 0; k < 16; k++) {
            fvec4 wv = *(const fvec4*)(OW + l * 64 + k * 4);
            fvec4 xv = *(const fvec4*)(xb + k * 4);
            o += wv[0] * xv[0] + wv[1] * xv[1] + wv[2] * xv[2] + wv[3] * xv[3];
        }
        ob[l] = o;
    }
    __syncthreads();
    if (l == 0) {
        float m = ob[0];
#pragma unroll
        for (int i = 1; i < 10; i++) m = fmaxf(m, ob[i]);
        float sum = 0.f;
#pragma unroll
        for (int i = 0; i < 10; i++) sum = sum + expf(ob[i] - m);
        float ls = logf(sum);
#pragma unroll
        for (int i = 0; i < 10; i++) out[i] = ob[i] - m - ls;
    }
}

extern "C" void kernel_launch(void* const* d_in, const int* in_sizes, int n_in,
                              void* d_out, int out_size, void* d_ws, size_t ws_size,
                              hipStream_t stream) {
    const float* values = (const float*)d_in[0];
    const int*   seg    = (const int*)d_in[1];
    const float* p1w0 = (const float*)d_in[2],  *p1b0 = (const float*)d_in[3];
    const float* p1w1 = (const float*)d_in[4],  *p1b1 = (const float*)d_in[5];
    const float* r1w0 = (const float*)d_in[6],  *r1b0 = (const float*)d_in[7];
    const float* r1w1 = (const float*)d_in[8],  *r1b1 = (const float*)d_in[9];
    const float* o1w  = (const float*)d_in[10], *o1b  = (const float*)d_in[11];
    const float* p2w0 = (const float*)d_in[12], *p2b0 = (const float*)d_in[13];
    const float* p2w1 = (const float*)d_in[14], *p2b1 = (const float*)d_in[15];
    const float* r2w0 = (const float*)d_in[16], *r2b0 = (const float*)d_in[17];
    const float* r2w1 = (const float*)d_in[18], *r2b1 = (const float*)d_in[19];
    const float* o2w  = (const float*)d_in[20], *o2b  = (const float*)d_in[21];

    float*  ev       = (float*)d_ws;                 // [NE][64]
    float*  s2       = ev + (size_t)NE * 64;         // [64]
    int*    off      = (int*)(s2 + 64);              // [NE+1]
    int*    counter  = off + (NE + 1);               // [1]
    float*  sorted_t = (float*)(counter + 1);        // [64]
    float2* tab      = (float2*)(sorted_t + 64);     // [65*64] (8B-aligned)

    hipLaunchKernelGGL(k_pre, dim3(NSEG), dim3(64), 0, stream,
                       p1w0, p1b0, p1w1, p1b1, sorted_t, tab);
    hipLaunchKernelGGL(k0_offsets, dim3((NT4 + 255) / 256), dim3(256), 0, stream,
                       seg, off, s2, counter);
    hipLaunchKernelGGL(k1_phi1, dim3(K1_BLOCKS), dim3(256), 0, stream,
                       values, off, sorted_t, tab, ev);
    hipLaunchKernelGGL(k2_events, dim3(K2_BLOCKS), dim3(64), 0, stream,
                       ev, r1w0, r1b0, r1w1, r1b1, o1w, o1b,
                       p2w0, p2b0, p2w1, p2b1, s2, counter,
                       r2w0, r2b0, r2w1, r2b1, o2w, o2b, (float*)d_out);
}

// Round 16
// 81.420 us; speedup vs baseline: 1.2167x; 1.2167x over previous
//
#include <hip/hip_runtime.h>

#define NT 2000000
#define NE 20000
#define NT4 (NT / 4)          // 500000, exact
#define K1_BLOCKS 1024
#define K1_WAVES (K1_BLOCKS * 4)   // 4096 -> 4.88 events/wave
#define K2_BLOCKS ((NE + 63) / 64) // 313
#define NSEG 65

using half8  = __attribute__((ext_vector_type(8))) _Float16;
using f32x4  = __attribute__((ext_vector_type(4))) float;
using fvec4  = __attribute__((ext_vector_type(4))) float;

// 8 consecutive f32 -> f16x8
__device__ __forceinline__ half8 load_h8(const float* __restrict__ p) {
    fvec4 a = *(const fvec4*)p;
    fvec4 b = *(const fvec4*)(p + 4);
    half8 r;
#pragma unroll
    for (int e = 0; e < 4; e++) {
        r[e]     = (_Float16)a[e];
        r[e + 4] = (_Float16)b[e];
    }
    return r;
}

// ---------------- K_PRE: piecewise-linear table for phi1 (r15, validated) -------
__global__ __launch_bounds__(64) void k_pre(
    const float* __restrict__ w0, const float* __restrict__ b0,
    const float* __restrict__ w1, const float* __restrict__ b1,
    float* __restrict__ sorted_t, float2* __restrict__ tab) {
    __shared__ float tS[64], w0S[64], b0S[64];
    __shared__ int rankS[64], styleS[64];
    const int k = threadIdx.x;
    const float w = w0[k], b = b0[k];
    float t; int style;
    if (w != 0.f) { t = -b / w; style = (w > 0.f) ? 1 : 0; }
    else          { t = (b > 0.f) ? -INFINITY : INFINITY; style = 1; }
    tS[k] = t; w0S[k] = w; b0S[k] = b; styleS[k] = style;
    __syncthreads();
    int rank = 0;
    for (int i = 0; i < 64; i++) {
        const float ti = tS[i];
        rank += (ti < t || (ti == t && i < k)) ? 1 : 0;
    }
    rankS[k] = rank;
    __syncthreads();
    if (blockIdx.x == 0) sorted_t[rank] = t;

    const int s = blockIdx.x;              // segment 0..64
    float a = 0.f, c = b1[k];              // thread k = output feature j
    for (int kk = 0; kk < 64; kk++) {
        const bool act = styleS[kk] ? (s > rankS[kk]) : (s <= rankS[kk]);
        if (act) {
            const float wjk = w1[k * 64 + kk];
            a = fmaf(wjk, w0S[kk], a);
            c = fmaf(wjk, b0S[kk], c);
        }
    }
    tab[s * 64 + k] = make_float2(a, c);
}

// ---------------- K0: event offsets via boundary scatter + zero s2/counter -------
__global__ __launch_bounds__(256) void k0_offsets(
    const int* __restrict__ seg, int* __restrict__ off, float* __restrict__ s2,
    int* __restrict__ counter) {
    if (blockIdx.x == 0) {
        if (threadIdx.x < 64) s2[threadIdx.x] = 0.f;
        if (threadIdx.x == 64) *counter = 0;
    }
    const int g = blockIdx.x * 256 + threadIdx.x;
    if (g >= NT4) return;
    const int idx4 = g * 4;
    const int4 s = *(const int4*)(seg + idx4);
    int prev = (g == 0) ? -1 : seg[idx4 - 1];
    int vals[4] = {s.x, s.y, s.z, s.w};
#pragma unroll
    for (int k = 0; k < 4; k++) {
        const int cur = vals[k];
        if (cur != prev) {
            for (int e = prev + 1; e <= cur; ++e) off[e] = idx4 + k;
        }
        prev = cur;
    }
    if (idx4 + 3 == NT - 1) {
        for (int e = prev + 1; e <= NE; ++e) off[e] = NT;
    }
}

// ---------------- K1: phi1 via PWL table + per-event sum (readlane broadcast) ----
// r15 post-mortem: __shfl = ds_bpermute -> 2 DS ops/particle = 39us of LDS
// issue. readlane (imm lane) is 1 VALU, result in SGPR: v_cmp takes the
// scalar, popcount is s_bcnt1, fma reads 1 SGPR. Per particle: 1 DS op only.
// 4 rotating accumulators = 4 independent ds_read latency chains.
__global__ __launch_bounds__(256) void k1_phi1(
    const float* __restrict__ values, const int* __restrict__ off,
    const float* __restrict__ sorted_t, const float2* __restrict__ gtab,
    float* __restrict__ ev) {
    __shared__ __align__(16) float2 tab[NSEG * 64];   // 33280 B -> 4 blocks/CU
    const int tid = threadIdx.x;
    const int w = tid >> 6, l = tid & 63;

    for (int idx = tid; idx < NSEG * 64; idx += 256) tab[idx] = gtab[idx];
    const float t_l = sorted_t[l];
    __syncthreads();

    const int wid = blockIdx.x * 4 + w;
    for (int e = wid; e < NE; e += K1_WAVES) {
        const int ps = off[e], pe = off[e + 1];
        float a0 = 0.f, a1 = 0.f, a2 = 0.f, a3 = 0.f;

        for (int base = ps; base < pe; base += 64) {
            const int cnt = min(pe - base, 64);       // uniform
            const float v_l = (base + l < pe) ? values[base + l] : 0.f;
            const int v_li = __float_as_int(v_l);

            // one particle: scalar broadcast -> wave ballot -> LDS (a,c) -> fma
            auto PROC = [&](int i, float& acc) {
                const float vs =
                    __int_as_float(__builtin_amdgcn_readlane(v_li, i));
                const int sg = (int)__popcll(__ballot(vs > t_l));
                const float2 ac = tab[sg * 64 + l];
                acc += fmaxf(fmaf(ac.x, vs, ac.y), 0.f);
            };

            const int full = cnt >> 2;                // groups of 4
#pragma unroll
            for (int g = 0; g < 16; ++g) {
                if (g >= full) break;                 // uniform break
                PROC(4 * g,     a0);                  // compile-time lanes ->
                PROC(4 * g + 1, a1);                  // v_readlane imm
                PROC(4 * g + 2, a2);
                PROC(4 * g + 3, a3);
            }
            const int tb = full * 4;                  // tail (runtime lane idx,
            if (tb     < cnt) PROC(tb,     a0);       // uniform -> s-reg lane)
            if (tb + 1 < cnt) PROC(tb + 1, a1);
            if (tb + 2 < cnt) PROC(tb + 2, a2);
        }
        ev[(size_t)e * 64 + l] = (a0 + a1) + (a2 + a3);   // lane l = feature l
    }
}

// ------- K2: rho1+o1+phi2 (5 fused layers, f16 single) + event-sum + k3 tail -----
// (byte-identical to r14/r15: 64-event/wave, 313 blocks, last-block rho2 tail)
__global__ __launch_bounds__(64) void k2_events(
    const float* __restrict__ ev,
    const float* __restrict__ W0, const float* __restrict__ B0,
    const float* __restrict__ W1, const float* __restrict__ B1,
    const float* __restrict__ W2, const float* __restrict__ B2,
    const float* __restrict__ W3, const float* __restrict__ B3,
    const float* __restrict__ W4, const float* __restrict__ B4,
    float* __restrict__ s2, int* __restrict__ counter,
    const float* __restrict__ R0, const float* __restrict__ Rb0,
    const float* __restrict__ R1, const float* __restrict__ Rb1,
    const float* __restrict__ OW, const float* __restrict__ OB,
    float* __restrict__ out) {
    __shared__ __align__(16) _Float16 xt[64 * 72];   // [e][k], stride 72
    const int l   = threadIdx.x;
    const int l15 = l & 15;
    const int l4  = l >> 4;
    const int ebase = blockIdx.x * 64;

    const float* Ws[5] = {W0, W1, W2, W3, W4};
    const float* Bs[5] = {B0, B1, B2, B3, B4};

    half8 A[4][2];
#pragma unroll
    for (int pf = 0; pf < 4; pf++) {
        const int e = ebase + pf * 16 + l15;
#pragma unroll
        for (int kf = 0; kf < 2; kf++) {
            half8 a;
            if (e < NE) {
                a = load_h8(ev + (size_t)e * 64 + kf * 32 + l4 * 8);
            } else {
#pragma unroll
                for (int e2 = 0; e2 < 8; e2++) a[e2] = (_Float16)0.f;
            }
            A[pf][kf] = a;
        }
    }

#pragma unroll
    for (int L = 0; L < 5; L++) {
        half8 Bh[2][4];
#pragma unroll
        for (int kf = 0; kf < 2; kf++)
#pragma unroll
            for (int jf = 0; jf < 4; jf++)
                Bh[kf][jf] = load_h8(Ws[L] + (jf * 16 + l15) * 64 +
                                     kf * 32 + l4 * 8);

        f32x4 acc[4][4];
#pragma unroll
        for (int jf = 0; jf < 4; jf++) {
            const float bj = Bs[L][jf * 16 + l15];
#pragma unroll
            for (int pf = 0; pf < 4; pf++)
#pragma unroll
                for (int r = 0; r < 4; r++) acc[pf][jf][r] = bj;
        }
#pragma unroll
        for (int kf = 0; kf < 2; kf++)
#pragma unroll
            for (int pf = 0; pf < 4; pf++)
#pragma unroll
                for (int jf = 0; jf < 4; jf++)
                    acc[pf][jf] = __builtin_amdgcn_mfma_f32_16x16x32_f16(
                        A[pf][kf], Bh[kf][jf], acc[pf][jf], 0, 0, 0);

        if (L < 4) {
#pragma unroll
            for (int pf = 0; pf < 4; pf++)
#pragma unroll
                for (int jf = 0; jf < 4; jf++) {
                    const int j = jf * 16 + l15;
#pragma unroll
                    for (int r = 0; r < 4; r++)
                        xt[(pf * 16 + l4 * 4 + r) * 72 + j] =
                            (_Float16)fmaxf(acc[pf][jf][r], 0.f);
                }
#pragma unroll
            for (int pf = 0; pf < 4; pf++)
#pragma unroll
                for (int kf = 0; kf < 2; kf++)
                    A[pf][kf] = *(const half8*)(xt + (pf * 16 + l15) * 72 +
                                                kf * 32 + l4 * 8);
        } else {
            float sj[4];
#pragma unroll
            for (int jf = 0; jf < 4; jf++) {
                float s = 0.f;
#pragma unroll
                for (int pf = 0; pf < 4; pf++)
#pragma unroll
                    for (int r = 0; r < 4; r++) {
                        const int e = ebase + pf * 16 + l4 * 4 + r;
                        float v = fmaxf(acc[pf][jf][r], 0.f);
                        s += (e < NE) ? v : 0.f;
                    }
                s += __shfl_xor(s, 16);
                s += __shfl_xor(s, 32);
                sj[jf] = s;
            }
            float v = (l4 == 0) ? sj[0] : (l4 == 1) ? sj[1]
                    : (l4 == 2) ? sj[2] : sj[3];
            atomicAdd(s2 + l, v);
        }
    }

    // ---- fused rho2 + output + log_softmax: last block to finish does it ----
    __shared__ int is_last;
    __threadfence();
    if (l == 0) {
        const int c = atomicAdd(counter, 1);
        is_last = (c == (int)gridDim.x - 1);
    }
    __syncthreads();
    if (!is_last) return;

    __shared__ __align__(16) float xb[64];
    __shared__ __align__(16) float yb[64];
    __shared__ float ob[10];

    xb[l] = atomicAdd(s2 + l, 0.f);   // coherent read (fence+counter ordered)
    __syncthreads();

    float a0 = Rb0[l];
#pragma unroll
    for (int k = 0; k < 16; k++) {
        fvec4 wv = *(const fvec4*)(R0 + l * 64 + k * 4);
        fvec4 xv = *(const fvec4*)(xb + k * 4);
        a0 += wv[0] * xv[0] + wv[1] * xv[1] + wv[2] * xv[2] + wv[3] * xv[3];
    }
    yb[l] = fmaxf(a0, 0.f);
    __syncthreads();

    float b_ = Rb1[l];
#pragma unroll
    for (int k = 0; k < 16; k++) {
        fvec4 wv = *(const fvec4*)(R1 + l * 64 + k * 4);
        fvec4 xv = *(const fvec4*)(yb + k * 4);
        b_ += wv[0] * xv[0] + wv[1] * xv[1] + wv[2] * xv[2] + wv[3] * xv[3];
    }
    __syncthreads();
    xb[l] = fmaxf(b_, 0.f);
    __syncthreads();

    if (l < 10) {
        float o = OB[l];
#pragma unroll
        for (int k = 0; k < 16; k++) {
            fvec4 wv = *(const fvec4*)(OW + l * 64 + k * 4);
            fvec4 xv = *(const fvec4*)(xb + k * 4);
            o += wv[0] * xv[0] + wv[1] * xv[1] + wv[2] * xv[2] + wv[3] * xv[3];
        }
        ob[l] = o;
    }
    __syncthreads();
    if (l == 0) {
        float m = ob[0];
#pragma unroll
        for (int i = 1; i < 10; i++) m = fmaxf(m, ob[i]);
        float sum = 0.f;
#pragma unroll
        for (int i = 0; i < 10; i++) sum = sum + expf(ob[i] - m);
        float ls = logf(sum);
#pragma unroll
        for (int i = 0; i < 10; i++) out[i] = ob[i] - m - ls;
    }
}

extern "C" void kernel_launch(void* const* d_in, const int* in_sizes, int n_in,
                              void* d_out, int out_size, void* d_ws, size_t ws_size,
                              hipStream_t stream) {
    const float* values = (const float*)d_in[0];
    const int*   seg    = (const int*)d_in[1];
    const float* p1w0 = (const float*)d_in[2],  *p1b0 = (const float*)d_in[3];
    const float* p1w1 = (const float*)d_in[4],  *p1b1 = (const float*)d_in[5];
    const float* r1w0 = (const float*)d_in[6],  *r1b0 = (const float*)d_in[7];
    const float* r1w1 = (const float*)d_in[8],  *r1b1 = (const float*)d_in[9];
    const float* o1w  = (const float*)d_in[10], *o1b  = (const float*)d_in[11];
    const float* p2w0 = (const float*)d_in[12], *p2b0 = (const float*)d_in[13];
    const float* p2w1 = (const float*)d_in[14], *p2b1 = (const float*)d_in[15];
    const float* r2w0 = (const float*)d_in[16], *r2b0 = (const float*)d_in[17];
    const float* r2w1 = (const float*)d_in[18], *r2b1 = (const float*)d_in[19];
    const float* o2w  = (const float*)d_in[20], *o2b  = (const float*)d_in[21];

    float*  ev       = (float*)d_ws;                 // [NE][64]
    float*  s2       = ev + (size_t)NE * 64;         // [64]
    int*    off      = (int*)(s2 + 64);              // [NE+1]
    int*    counter  = off + (NE + 1);               // [1]
    float*  sorted_t = (float*)(counter + 1);        // [64]
    float2* tab      = (float2*)(sorted_t + 64);     // [65*64] (8B-aligned)

    hipLaunchKernelGGL(k_pre, dim3(NSEG), dim3(64), 0, stream,
                       p1w0, p1b0, p1w1, p1b1, sorted_t, tab);
    hipLaunchKernelGGL(k0_offsets, dim3((NT4 + 255) / 256), dim3(256), 0, stream,
                       seg, off, s2, counter);
    hipLaunchKernelGGL(k1_phi1, dim3(K1_BLOCKS), dim3(256), 0, stream,
                       values, off, sorted_t, tab, ev);
    hipLaunchKernelGGL(k2_events, dim3(K2_BLOCKS), dim3(64), 0, stream,
                       ev, r1w0, r1b0, r1w1, r1b1, o1w, o1b,
                       p2w0, p2b0, p2w1, p2b1, s2, counter,
                       r2w0, r2b0, r2w1, r2b1, o2w, o2b, (float*)d_out);
}

// Round 17
// 74.520 us; speedup vs baseline: 1.3293x; 1.0926x over previous
//
#include <hip/hip_runtime.h>

#define NT 2000000
#define NE 20000
#define NT4 (NT / 4)          // 500000, exact
#define K1_BLOCKS 2048
#define K1_WAVES (K1_BLOCKS * 4)   // 8192 waves; 8 blocks/CU resident
#define K2_BLOCKS ((NE + 63) / 64) // 313
#define NSEG 65
#define K0_BLOCKS ((NT4 + 255) / 256)  // 1954

using half8  = __attribute__((ext_vector_type(8))) _Float16;
using half2v = __attribute__((ext_vector_type(2))) _Float16;
using f32x4  = __attribute__((ext_vector_type(4))) float;
using fvec4  = __attribute__((ext_vector_type(4))) float;

// 8 consecutive f32 -> f16x8
__device__ __forceinline__ half8 load_h8(const float* __restrict__ p) {
    fvec4 a = *(const fvec4*)p;
    fvec4 b = *(const fvec4*)(p + 4);
    half8 r;
#pragma unroll
    for (int e = 0; e < 4; e++) {
        r[e]     = (_Float16)a[e];
        r[e + 4] = (_Float16)b[e];
    }
    return r;
}

// ---------------- K0 (fused): PWL table (blocks<65) + offsets + zero s2/counter --
// k_pre logic validated r15/r16; folded here to save a dispatch+gap. Blocks
// 0..64 compute table segment s=blockIdx (threads 0-63); ALL blocks then do
// the offsets scatter. Barriers are block-uniform (branch on blockIdx only).
__global__ __launch_bounds__(256) void k0_fused(
    const int* __restrict__ seg, int* __restrict__ off, float* __restrict__ s2,
    int* __restrict__ counter,
    const float* __restrict__ w0, const float* __restrict__ b0,
    const float* __restrict__ w1, const float* __restrict__ b1,
    float* __restrict__ sorted_t, half2v* __restrict__ tabg) {
    if (blockIdx.x < NSEG) {
        __shared__ float tS[64], w0S[64], b0S[64];
        __shared__ int rankS_unused[1];   // (kept minimal; rank stays in reg)
        __shared__ int styleS[64];
        const int k = threadIdx.x;
        float t = 0.f; int rank = 0;
        if (k < 64) {
            const float w = w0[k], b = b0[k];
            int style;
            if (w != 0.f) { t = -b / w; style = (w > 0.f) ? 1 : 0; }
            else          { t = (b > 0.f) ? -INFINITY : INFINITY; style = 1; }
            tS[k] = t; w0S[k] = w; b0S[k] = b; styleS[k] = style;
        }
        __syncthreads();
        if (k < 64) {
            for (int i = 0; i < 64; i++) {
                const float ti = tS[i];
                rank += (ti < t || (ti == t && i < k)) ? 1 : 0;
            }
        }
        __syncthreads();
        // rankS needed by the (a,c) pass -> recompute activity from rank via
        // shared: store ranks in styleS-adjacent shared arr
        __shared__ int rankS[64];
        if (k < 64) rankS[k] = rank;
        __syncthreads();
        if (k < 64) {
            if (blockIdx.x == 0) sorted_t[rank] = t;
            const int s = blockIdx.x;          // segment 0..64
            float a = 0.f, c = b1[k];          // thread k = output feature j
            for (int kk = 0; kk < 64; kk++) {
                const bool act = styleS[kk] ? (s > rankS[kk]) : (s <= rankS[kk]);
                if (act) {
                    const float wjk = w1[k * 64 + kk];
                    a = fmaf(wjk, w0S[kk], a);
                    c = fmaf(wjk, b0S[kk], c);
                }
            }
            tabg[s * 64 + k] = half2v{(_Float16)a, (_Float16)c};
        }
    }

    // ---- offsets scatter (all blocks) ----
    if (blockIdx.x == 0) {
        if (threadIdx.x < 64) s2[threadIdx.x] = 0.f;
        if (threadIdx.x == 64) *counter = 0;
    }
    const int g = blockIdx.x * 256 + threadIdx.x;
    if (g >= NT4) return;
    const int idx4 = g * 4;
    const int4 s = *(const int4*)(seg + idx4);
    int prev = (g == 0) ? -1 : seg[idx4 - 1];
    int vals[4] = {s.x, s.y, s.z, s.w};
#pragma unroll
    for (int k = 0; k < 4; k++) {
        const int cur = vals[k];
        if (cur != prev) {
            for (int e = prev + 1; e <= cur; ++e) off[e] = idx4 + k;
        }
        prev = cur;
    }
    if (idx4 + 3 == NT - 1) {
        for (int e = prev + 1; e <= NE; ++e) off[e] = NT;
    }
}

// ---------------- K1: phi1 via PWL table (f16-packed) + per-event sum ------------
// r16 post-mortem: ds_read_b64 per particle = 26-39us/CU of LDS issue (the
// binding pipe). f16x2-packed (a,c) -> ds_read_b32 (5.8cy) + v_fma_mix
// consumption; 16.6KB table -> 8 blocks/CU (grid 2048) doubles residency.
// Per-wave event-count quantization absorbed at CU level by 32-wave multiplex.
__global__ __launch_bounds__(256) void k1_phi1(
    const float* __restrict__ values, const int* __restrict__ off,
    const float* __restrict__ sorted_t, const half2v* __restrict__ gtab,
    float* __restrict__ ev) {
    __shared__ __align__(16) half2v tab[NSEG * 64];   // 16640 B
    const int tid = threadIdx.x;
    const int w = tid >> 6, l = tid & 63;

    for (int idx = tid; idx < NSEG * 64; idx += 256) tab[idx] = gtab[idx];
    const float t_l = sorted_t[l];
    __syncthreads();

    const int wid = blockIdx.x * 4 + w;
    for (int e = wid; e < NE; e += K1_WAVES) {
        const int ps = off[e], pe = off[e + 1];
        float a0 = 0.f, a1 = 0.f, a2 = 0.f, a3 = 0.f;

        for (int base = ps; base < pe; base += 64) {
            const int cnt = min(pe - base, 64);       // uniform
            const float v_l = (base + l < pe) ? values[base + l] : 0.f;
            const int v_li = __float_as_int(v_l);

            // one particle: scalar broadcast -> ballot seg -> LDS b32 -> fma_mix
            auto PROC = [&](int i, float& acc) {
                const float vs =
                    __int_as_float(__builtin_amdgcn_readlane(v_li, i));
                const int sg = (int)__popcll(__ballot(vs > t_l));
                const half2v ac = tab[sg * 64 + l];
                acc += fmaxf(fmaf((float)ac[0], vs, (float)ac[1]), 0.f);
            };

            const int full = cnt >> 2;                // groups of 4
#pragma unroll
            for (int g = 0; g < 16; ++g) {
                if (g >= full) break;                 // uniform break
                PROC(4 * g,     a0);
                PROC(4 * g + 1, a1);
                PROC(4 * g + 2, a2);
                PROC(4 * g + 3, a3);
            }
            const int tb = full * 4;                  // tail (runtime lane idx)
            if (tb     < cnt) PROC(tb,     a0);
            if (tb + 1 < cnt) PROC(tb + 1, a1);
            if (tb + 2 < cnt) PROC(tb + 2, a2);
        }
        ev[(size_t)e * 64 + l] = (a0 + a1) + (a2 + a3);   // lane l = feature l
    }
}

// ------- K2: rho1+o1+phi2 (5 fused layers, f16 single) + event-sum + k3 tail -----
// (byte-identical to r14-r16: 64-event/wave, 313 blocks, last-block rho2 tail)
__global__ __launch_bounds__(64) void k2_events(
    const float* __restrict__ ev,
    const float* __restrict__ W0, const float* __restrict__ B0,
    const float* __restrict__ W1, const float* __restrict__ B1,
    const float* __restrict__ W2, const float* __restrict__ B2,
    const float* __restrict__ W3, const float* __restrict__ B3,
    const float* __restrict__ W4, const float* __restrict__ B4,
    float* __restrict__ s2, int* __restrict__ counter,
    const float* __restrict__ R0, const float* __restrict__ Rb0,
    const float* __restrict__ R1, const float* __restrict__ Rb1,
    const float* __restrict__ OW, const float* __restrict__ OB,
    float* __restrict__ out) {
    __shared__ __align__(16) _Float16 xt[64 * 72];   // [e][k], stride 72
    const int l   = threadIdx.x;
    const int l15 = l & 15;
    const int l4  = l >> 4;
    const int ebase = blockIdx.x * 64;

    const float* Ws[5] = {W0, W1, W2, W3, W4};
    const float* Bs[5] = {B0, B1, B2, B3, B4};

    half8 A[4][2];
#pragma unroll
    for (int pf = 0; pf < 4; pf++) {
        const int e = ebase + pf * 16 + l15;
#pragma unroll
        for (int kf = 0; kf < 2; kf++) {
            half8 a;
            if (e < NE) {
                a = load_h8(ev + (size_t)e * 64 + kf * 32 + l4 * 8);
            } else {
#pragma unroll
                for (int e2 = 0; e2 < 8; e2++) a[e2] = (_Float16)0.f;
            }
            A[pf][kf] = a;
        }
    }

#pragma unroll
    for (int L = 0; L < 5; L++) {
        half8 Bh[2][4];
#pragma unroll
        for (int kf = 0; kf < 2; kf++)
#pragma unroll
            for (int jf = 0; jf < 4; jf++)
                Bh[kf][jf] = load_h8(Ws[L] + (jf * 16 + l15) * 64 +
                                     kf * 32 + l4 * 8);

        f32x4 acc[4][4];
#pragma unroll
        for (int jf = 0; jf < 4; jf++) {
            const float bj = Bs[L][jf * 16 + l15];
#pragma unroll
            for (int pf = 0; pf < 4; pf++)
#pragma unroll
                for (int r = 0; r < 4; r++) acc[pf][jf][r] = bj;
        }
#pragma unroll
        for (int kf = 0; kf < 2; kf++)
#pragma unroll
            for (int pf = 0; pf < 4; pf++)
#pragma unroll
                for (int jf = 0; jf < 4; jf++)
                    acc[pf][jf] = __builtin_amdgcn_mfma_f32_16x16x32_f16(
                        A[pf][kf], Bh[kf][jf], acc[pf][jf], 0, 0, 0);

        if (L < 4) {
#pragma unroll
            for (int pf = 0; pf < 4; pf++)
#pragma unroll
                for (int jf = 0; jf < 4; jf++) {
                    const int j = jf * 16 + l15;
#pragma unroll
                    for (int r = 0; r < 4; r++)
                        xt[(pf * 16 + l4 * 4 + r) * 72 + j] =
                            (_Float16)fmaxf(acc[pf][jf][r], 0.f);
                }
#pragma unroll
            for (int pf = 0; pf < 4; pf++)
#pragma unroll
                for (int kf = 0; kf < 2; kf++)
                    A[pf][kf] = *(const half8*)(xt + (pf * 16 + l15) * 72 +
                                                kf * 32 + l4 * 8);
        } else {
            float sj[4];
#pragma unroll
            for (int jf = 0; jf < 4; jf++) {
                float s = 0.f;
#pragma unroll
                for (int pf = 0; pf < 4; pf++)
#pragma unroll
                    for (int r = 0; r < 4; r++) {
                        const int e = ebase + pf * 16 + l4 * 4 + r;
                        float v = fmaxf(acc[pf][jf][r], 0.f);
                        s += (e < NE) ? v : 0.f;
                    }
                s += __shfl_xor(s, 16);
                s += __shfl_xor(s, 32);
                sj[jf] = s;
            }
            float v = (l4 == 0) ? sj[0] : (l4 == 1) ? sj[1]
                    : (l4 == 2) ? sj[2] : sj[3];
            atomicAdd(s2 + l, v);
        }
    }

    // ---- fused rho2 + output + log_softmax: last block to finish does it ----
    __shared__ int is_last;
    __threadfence();
    if (l == 0) {
        const int c = atomicAdd(counter, 1);
        is_last = (c == (int)gridDim.x - 1);
    }
    __syncthreads();
    if (!is_last) return;

    __shared__ __align__(16) float xb[64];
    __shared__ __align__(16) float yb[64];
    __shared__ float ob[10];

    xb[l] = atomicAdd(s2 + l, 0.f);   // coherent read (fence+counter ordered)
    __syncthreads();

    float a0 = Rb0[l];
#pragma unroll
    for (int k = 0; k < 16; k++) {
        fvec4 wv = *(const fvec4*)(R0 + l * 64 + k * 4);
        fvec4 xv = *(const fvec4*)(xb + k * 4);
        a0 += wv[0] * xv[0] + wv[1] * xv[1] + wv[2] * xv[2] + wv[3] * xv[3];
    }
    yb[l] = fmaxf(a0, 0.f);
    __syncthreads();

    float b_ = Rb1[l];
#pragma unroll
    for (int k = 0; k < 16; k++) {
        fvec4 wv = *(const fvec4*)(R1 + l * 64 + k * 4);
        fvec4 xv = *(const fvec4*)(yb + k * 4);
        b_ += wv[0] * xv[0] + wv[1] * xv[1] + wv[2] * xv[2] + wv[3] * xv[3];
    }
    __syncthreads();
    xb[l] = fmaxf(b_, 0.f);
    __syncthreads();

    if (l < 10) {
        float o = OB[l];
#pragma unroll
        for (int k = 0; k < 16; k++) {
            fvec4 wv = *(const fvec4*)(OW + l * 64 + k * 4);
            fvec4 xv = *(const fvec4*)(xb + k * 4);
            o += wv[0] * xv[0] + wv[1] * xv[1] + wv[2] * xv[2] + wv[3] * xv[3];
        }
        ob[l] = o;
    }
    __syncthreads();
    if (l == 0) {
        float m = ob[0];
#pragma unroll
        for (int i = 1; i < 10; i++) m = fmaxf(m, ob[i]);
        float sum = 0.f;
#pragma unroll
        for (int i = 0; i < 10; i++) sum = sum + expf(ob[i] - m);
        float ls = logf(sum);
#pragma unroll
        for (int i = 0; i < 10; i++) out[i] = ob[i] - m - ls;
    }
}

extern "C" void kernel_launch(void* const* d_in, const int* in_sizes, int n_in,
                              void* d_out, int out_size, void* d_ws, size_t ws_size,
                              hipStream_t stream) {
    const float* values = (const float*)d_in[0];
    const int*   seg    = (const int*)d_in[1];
    const float* p1w0 = (const float*)d_in[2],  *p1b0 = (const float*)d_in[3];
    const float* p1w1 = (const float*)d_in[4],  *p1b1 = (const float*)d_in[5];
    const float* r1w0 = (const float*)d_in[6],  *r1b0 = (const float*)d_in[7];
    const float* r1w1 = (const float*)d_in[8],  *r1b1 = (const float*)d_in[9];
    const float* o1w  = (const float*)d_in[10], *o1b  = (const float*)d_in[11];
    const float* p2w0 = (const float*)d_in[12], *p2b0 = (const float*)d_in[13];
    const float* p2w1 = (const float*)d_in[14], *p2b1 = (const float*)d_in[15];
    const float* r2w0 = (const float*)d_in[16], *r2b0 = (const float*)d_in[17];
    const float* r2w1 = (const float*)d_in[18], *r2b1 = (const float*)d_in[19];
    const float* o2w  = (const float*)d_in[20], *o2b  = (const float*)d_in[21];

    float*  ev       = (float*)d_ws;                 // [NE][64]
    float*  s2       = ev + (size_t)NE * 64;         // [64]
    int*    off      = (int*)(s2 + 64);              // [NE+1]
    int*    counter  = off + (NE + 1);               // [1]
    float*  sorted_t = (float*)(counter + 1);        // [64]
    half2v* tabg     = (half2v*)(sorted_t + 64);     // [65*64] x 4B

    hipLaunchKernelGGL(k0_fused, dim3(K0_BLOCKS), dim3(256), 0, stream,
                       seg, off, s2, counter,
                       p1w0, p1b0, p1w1, p1b1, sorted_t, tabg);
    hipLaunchKernelGGL(k1_phi1, dim3(K1_BLOCKS), dim3(256), 0, stream,
                       values, off, sorted_t, tabg, ev);
    hipLaunchKernelGGL(k2_events, dim3(K2_BLOCKS), dim3(64), 0, stream,
                       ev, r1w0, r1b0, r1w1, r1b1, o1w, o1b,
                       p2w0, p2b0, p2w1, p2b1, s2, counter,
                       r2w0, r2b0, r2w1, r2b1, o2w, o2b, (float*)d_out);
}

// Round 18
// 74.494 us; speedup vs baseline: 1.3298x; 1.0003x over previous
//
#include <hip/hip_runtime.h>

#define NT 2000000
#define NE 20000
#define NT4 (NT / 4)          // 500000, exact
#define K1_BLOCKS 2048
#define K1_WAVES (K1_BLOCKS * 4)   // 8192 waves; 8 blocks/CU resident
#define K2_BLOCKS ((NE + 63) / 64) // 313
#define NSEG 65
#define K0_BLOCKS ((NT4 + 255) / 256)  // 1954

using half8  = __attribute__((ext_vector_type(8))) _Float16;
using half4v = __attribute__((ext_vector_type(4))) _Float16;
using f32x4  = __attribute__((ext_vector_type(4))) float;
using fvec4  = __attribute__((ext_vector_type(4))) float;

// 8 consecutive f32 -> f16x8
__device__ __forceinline__ half8 load_h8(const float* __restrict__ p) {
    fvec4 a = *(const fvec4*)p;
    fvec4 b = *(const fvec4*)(p + 4);
    half8 r;
#pragma unroll
    for (int e = 0; e < 4; e++) {
        r[e]     = (_Float16)a[e];
        r[e + 4] = (_Float16)b[e];
    }
    return r;
}

// ---------------- K0 (fused): PWL table (blocks<65) + offsets + zero s2/counter --
// Table now PAIR-PACKED: tabg[s*32 + t] = {a[2t],c[2t],a[2t+1],c[2t+1]} f16x4,
// so k1 reads 2 features/lane via one ds_read_b64 serving TWO particles.
__global__ __launch_bounds__(256) void k0_fused(
    const int* __restrict__ seg, int* __restrict__ off, float* __restrict__ s2,
    int* __restrict__ counter,
    const float* __restrict__ w0, const float* __restrict__ b0,
    const float* __restrict__ w1, const float* __restrict__ b1,
    float* __restrict__ sorted_t, half4v* __restrict__ tabg) {
    if (blockIdx.x < NSEG) {
        __shared__ float tS[64], w0S[64], b0S[64], aS[64], cS[64];
        __shared__ int styleS[64], rankS[64];
        const int k = threadIdx.x;
        float t = 0.f; int rank = 0;
        if (k < 64) {
            const float w = w0[k], b = b0[k];
            int style;
            if (w != 0.f) { t = -b / w; style = (w > 0.f) ? 1 : 0; }
            else          { t = (b > 0.f) ? -INFINITY : INFINITY; style = 1; }
            tS[k] = t; w0S[k] = w; b0S[k] = b; styleS[k] = style;
        }
        __syncthreads();
        if (k < 64) {
            for (int i = 0; i < 64; i++) {
                const float ti = tS[i];
                rank += (ti < t || (ti == t && i < k)) ? 1 : 0;
            }
            rankS[k] = rank;
        }
        __syncthreads();
        if (k < 64) {
            if (blockIdx.x == 0) sorted_t[rank] = t;
            const int s = blockIdx.x;          // segment 0..64
            float a = 0.f, c = b1[k];          // thread k = output feature j
            for (int kk = 0; kk < 64; kk++) {
                const bool act = styleS[kk] ? (s > rankS[kk]) : (s <= rankS[kk]);
                if (act) {
                    const float wjk = w1[k * 64 + kk];
                    a = fmaf(wjk, w0S[kk], a);
                    c = fmaf(wjk, b0S[kk], c);
                }
            }
            aS[k] = a; cS[k] = c;
        }
        __syncthreads();
        if (k < 32) {
            const int s = blockIdx.x;
            tabg[s * 32 + k] = half4v{
                (_Float16)aS[2 * k],     (_Float16)cS[2 * k],
                (_Float16)aS[2 * k + 1], (_Float16)cS[2 * k + 1]};
        }
    }

    // ---- offsets scatter (all blocks) ----
    if (blockIdx.x == 0) {
        if (threadIdx.x < 64) s2[threadIdx.x] = 0.f;
        if (threadIdx.x == 64) *counter = 0;
    }
    const int g = blockIdx.x * 256 + threadIdx.x;
    if (g >= NT4) return;
    const int idx4 = g * 4;
    const int4 s = *(const int4*)(seg + idx4);
    int prev = (g == 0) ? -1 : seg[idx4 - 1];
    int vals[4] = {s.x, s.y, s.z, s.w};
#pragma unroll
    for (int k = 0; k < 4; k++) {
        const int cur = vals[k];
        if (cur != prev) {
            for (int e = prev + 1; e <= cur; ++e) off[e] = idx4 + k;
        }
        prev = cur;
    }
    if (idx4 + 3 == NT - 1) {
        for (int e = prev + 1; e <= NE; ++e) off[e] = NT;
    }
}

// ---------------- K1: phi1 via PWL table, PAIR-PACKED + per-event sum ------------
// r17 post-mortem: DS issue (1 ds_read_b32/particle, 5.8cy) = ~19us/CU floor
// and only 4 latency chains. Pairing: lanes 0-31 = particle A (2 features
// each), lanes 32-63 = particle B -> ONE ds_read_b64 per 2 particles. 4 pair
// chains = 8 particles in flight. ev stored by lanes 0-31 as float2 (feature
// order unchanged -> k2 untouched).
__global__ __launch_bounds__(256) void k1_phi1(
    const float* __restrict__ values, const int* __restrict__ off,
    const float* __restrict__ sorted_t, const half4v* __restrict__ gtab,
    float* __restrict__ ev) {
    __shared__ __align__(16) half4v tab[NSEG * 32];   // 16640 B
    const int tid = threadIdx.x;
    const int w = tid >> 6, l = tid & 63;
    const int l31 = l & 31;
    const bool lo32 = (l < 32);

    for (int idx = tid; idx < NSEG * 32; idx += 256) tab[idx] = gtab[idx];
    const float t_l = sorted_t[l];
    __syncthreads();

    const int wid = blockIdx.x * 4 + w;
    for (int e = wid; e < NE; e += K1_WAVES) {
        const int ps = off[e], pe = off[e + 1];
        float2 p0 = {0.f, 0.f}, p1 = {0.f, 0.f};
        float2 p2 = {0.f, 0.f}, p3 = {0.f, 0.f};

        for (int base = ps; base < pe; base += 64) {
            const int cnt = min(pe - base, 64);       // uniform
            const float v_l = (base + l < pe) ? values[base + l] : 0.f;
            const int v_li = __float_as_int(v_l);

            // 2 particles: A on lanes 0-31, B on lanes 32-63; 1 ds_read_b64
            auto PROC2 = [&](int i, int j, float2& acc) {
                const float vsA =
                    __int_as_float(__builtin_amdgcn_readlane(v_li, i));
                const float vsB =
                    __int_as_float(__builtin_amdgcn_readlane(v_li, j));
                const int sgA = (int)__popcll(__ballot(vsA > t_l));
                const int sgB = (int)__popcll(__ballot(vsB > t_l));
                const int sg  = lo32 ? sgA : sgB;
                const float vs = lo32 ? vsA : vsB;
                const half4v ac = tab[sg * 32 + l31];
                acc.x += fmaxf(fmaf((float)ac[0], vs, (float)ac[1]), 0.f);
                acc.y += fmaxf(fmaf((float)ac[2], vs, (float)ac[3]), 0.f);
            };
            // odd tail: particle A only, accumulate on lanes 0-31
            auto PROC1 = [&](int i, float2& acc) {
                const float vsA =
                    __int_as_float(__builtin_amdgcn_readlane(v_li, i));
                const int sgA = (int)__popcll(__ballot(vsA > t_l));
                const half4v ac = tab[sgA * 32 + l31];
                const float x = fmaxf(fmaf((float)ac[0], vsA, (float)ac[1]), 0.f);
                const float y = fmaxf(fmaf((float)ac[2], vsA, (float)ac[3]), 0.f);
                acc.x += lo32 ? x : 0.f;
                acc.y += lo32 ? y : 0.f;
            };

            const int fullg = cnt >> 3;               // groups of 8 particles
#pragma unroll
            for (int g = 0; g < 8; ++g) {
                if (g >= fullg) break;                // uniform break
                PROC2(8 * g,     8 * g + 1, p0);      // compile-time lanes
                PROC2(8 * g + 2, 8 * g + 3, p1);
                PROC2(8 * g + 4, 8 * g + 5, p2);
                PROC2(8 * g + 6, 8 * g + 7, p3);
            }
            int tb = fullg * 8;                       // remainder 0..7
            if (tb + 1 < cnt) { PROC2(tb, tb + 1, p0); tb += 2; }
            if (tb + 1 < cnt) { PROC2(tb, tb + 1, p1); tb += 2; }
            if (tb + 1 < cnt) { PROC2(tb, tb + 1, p2); tb += 2; }
            if (tb < cnt)     { PROC1(tb, p3); }
        }

        // fold B-half into A-half, store float2 per lane (feature order kept)
        float s0 = (p0.x + p1.x) + (p2.x + p3.x);
        float s1 = (p0.y + p1.y) + (p2.y + p3.y);
        s0 += __shfl_xor(s0, 32);
        s1 += __shfl_xor(s1, 32);
        if (lo32)
            *(float2*)(ev + (size_t)e * 64 + 2 * l31) = make_float2(s0, s1);
    }
}

// ------- K2: rho1+o1+phi2 (5 fused layers, f16 single) + event-sum + k3 tail -----
// (byte-identical to r14-r17: 64-event/wave, 313 blocks, last-block rho2 tail)
__global__ __launch_bounds__(64) void k2_events(
    const float* __restrict__ ev,
    const float* __restrict__ W0, const float* __restrict__ B0,
    const float* __restrict__ W1, const float* __restrict__ B1,
    const float* __restrict__ W2, const float* __restrict__ B2,
    const float* __restrict__ W3, const float* __restrict__ B3,
    const float* __restrict__ W4, const float* __restrict__ B4,
    float* __restrict__ s2, int* __restrict__ counter,
    const float* __restrict__ R0, const float* __restrict__ Rb0,
    const float* __restrict__ R1, const float* __restrict__ Rb1,
    const float* __restrict__ OW, const float* __restrict__ OB,
    float* __restrict__ out) {
    __shared__ __align__(16) _Float16 xt[64 * 72];   // [e][k], stride 72
    const int l   = threadIdx.x;
    const int l15 = l & 15;
    const int l4  = l >> 4;
    const int ebase = blockIdx.x * 64;

    const float* Ws[5] = {W0, W1, W2, W3, W4};
    const float* Bs[5] = {B0, B1, B2, B3, B4};

    half8 A[4][2];
#pragma unroll
    for (int pf = 0; pf < 4; pf++) {
        const int e = ebase + pf * 16 + l15;
#pragma unroll
        for (int kf = 0; kf < 2; kf++) {
            half8 a;
            if (e < NE) {
                a = load_h8(ev + (size_t)e * 64 + kf * 32 + l4 * 8);
            } else {
#pragma unroll
                for (int e2 = 0; e2 < 8; e2++) a[e2] = (_Float16)0.f;
            }
            A[pf][kf] = a;
        }
    }

#pragma unroll
    for (int L = 0; L < 5; L++) {
        half8 Bh[2][4];
#pragma unroll
        for (int kf = 0; kf < 2; kf++)
#pragma unroll
            for (int jf = 0; jf < 4; jf++)
                Bh[kf][jf] = load_h8(Ws[L] + (jf * 16 + l15) * 64 +
                                     kf * 32 + l4 * 8);

        f32x4 acc[4][4];
#pragma unroll
        for (int jf = 0; jf < 4; jf++) {
            const float bj = Bs[L][jf * 16 + l15];
#pragma unroll
            for (int pf = 0; pf < 4; pf++)
#pragma unroll
                for (int r = 0; r < 4; r++) acc[pf][jf][r] = bj;
        }
#pragma unroll
        for (int kf = 0; kf < 2; kf++)
#pragma unroll
            for (int pf = 0; pf < 4; pf++)
#pragma unroll
                for (int jf = 0; jf < 4; jf++)
                    acc[pf][jf] = __builtin_amdgcn_mfma_f32_16x16x32_f16(
                        A[pf][kf], Bh[kf][jf], acc[pf][jf], 0, 0, 0);

        if (L < 4) {
#pragma unroll
            for (int pf = 0; pf < 4; pf++)
#pragma unroll
                for (int jf = 0; jf < 4; jf++) {
                    const int j = jf * 16 + l15;
#pragma unroll
                    for (int r = 0; r < 4; r++)
                        xt[(pf * 16 + l4 * 4 + r) * 72 + j] =
                            (_Float16)fmaxf(acc[pf][jf][r], 0.f);
                }
#pragma unroll
            for (int pf = 0; pf < 4; pf++)
#pragma unroll
                for (int kf = 0; kf < 2; kf++)
                    A[pf][kf] = *(const half8*)(xt + (pf * 16 + l15) * 72 +
                                                kf * 32 + l4 * 8);
        } else {
            float sj[4];
#pragma unroll
            for (int jf = 0; jf < 4; jf++) {
                float s = 0.f;
#pragma unroll
                for (int pf = 0; pf < 4; pf++)
#pragma unroll
                    for (int r = 0; r < 4; r++) {
                        const int e = ebase + pf * 16 + l4 * 4 + r;
                        float v = fmaxf(acc[pf][jf][r], 0.f);
                        s += (e < NE) ? v : 0.f;
                    }
                s += __shfl_xor(s, 16);
                s += __shfl_xor(s, 32);
                sj[jf] = s;
            }
            float v = (l4 == 0) ? sj[0] : (l4 == 1) ? sj[1]
                    : (l4 == 2) ? sj[2] : sj[3];
            atomicAdd(s2 + l, v);
        }
    }

    // ---- fused rho2 + output + log_softmax: last block to finish does it ----
    __shared__ int is_last;
    __threadfence();
    if (l == 0) {
        const int c = atomicAdd(counter, 1);
        is_last = (c == (int)gridDim.x - 1);
    }
    __syncthreads();
    if (!is_last) return;

    __shared__ __align__(16) float xb[64];
    __shared__ __align__(16) float yb[64];
    __shared__ float ob[10];

    xb[l] = atomicAdd(s2 + l, 0.f);   // coherent read (fence+counter ordered)
    __syncthreads();

    float a0 = Rb0[l];
#pragma unroll
    for (int k = 0; k < 16; k++) {
        fvec4 wv = *(const fvec4*)(R0 + l * 64 + k * 4);
        fvec4 xv = *(const fvec4*)(xb + k * 4);
        a0 += wv[0] * xv[0] + wv[1] * xv[1] + wv[2] * xv[2] + wv[3] * xv[3];
    }
    yb[l] = fmaxf(a0, 0.f);
    __syncthreads();

    float b_ = Rb1[l];
#pragma unroll
    for (int k = 0; k < 16; k++) {
        fvec4 wv = *(const fvec4*)(R1 + l * 64 + k * 4);
        fvec4 xv = *(const fvec4*)(yb + k * 4);
        b_ += wv[0] * xv[0] + wv[1] * xv[1] + wv[2] * xv[2] + wv[3] * xv[3];
    }
    __syncthreads();
    xb[l] = fmaxf(b_, 0.f);
    __syncthreads();

    if (l < 10) {
        float o = OB[l];
#pragma unroll
        for (int k = 0; k < 16; k++) {
            fvec4 wv = *(const fvec4*)(OW + l * 64 + k * 4);
            fvec4 xv = *(const fvec4*)(xb + k * 4);
            o += wv[0] * xv[0] + wv[1] * xv[1] + wv[2] * xv[2] + wv[3] * xv[3];
        }
        ob[l] = o;
    }
    __syncthreads();
    if (l == 0) {
        float m = ob[0];
#pragma unroll
        for (int i = 1; i < 10; i++) m = fmaxf(m, ob[i]);
        float sum = 0.f;
#pragma unroll
        for (int i = 0; i < 10; i++) sum = sum + expf(ob[i] - m);
        float ls = logf(sum);
#pragma unroll
        for (int i = 0; i < 10; i++) out[i] = ob[i] - m - ls;
    }
}

extern "C" void kernel_launch(void* const* d_in, const int* in_sizes, int n_in,
                              void* d_out, int out_size, void* d_ws, size_t ws_size,
                              hipStream_t stream) {
    const float* values = (const float*)d_in[0];
    const int*   seg    = (const int*)d_in[1];
    const float* p1w0 = (const float*)d_in[2],  *p1b0 = (const float*)d_in[3];
    const float* p1w1 = (const float*)d_in[4],  *p1b1 = (const float*)d_in[5];
    const float* r1w0 = (const float*)d_in[6],  *r1b0 = (const float*)d_in[7];
    const float* r1w1 = (const float*)d_in[8],  *r1b1 = (const float*)d_in[9];
    const float* o1w  = (const float*)d_in[10], *o1b  = (const float*)d_in[11];
    const float* p2w0 = (const float*)d_in[12], *p2b0 = (const float*)d_in[13];
    const float* p2w1 = (const float*)d_in[14], *p2b1 = (const float*)d_in[15];
    const float* r2w0 = (const float*)d_in[16], *r2b0 = (const float*)d_in[17];
    const float* r2w1 = (const float*)d_in[18], *r2b1 = (const float*)d_in[19];
    const float* o2w  = (const float*)d_in[20], *o2b  = (const float*)d_in[21];

    float*  ev       = (float*)d_ws;                 // [NE][64]
    float*  s2       = ev + (size_t)NE * 64;         // [64]
    int*    off      = (int*)(s2 + 64);              // [NE+1]
    int*    counter  = off + (NE + 1);               // [1]
    float*  sorted_t = (float*)(counter + 1);        // [64]
    half4v* tabg     = (half4v*)(sorted_t + 64);     // [65*32] x 8B (8B-aligned)

    hipLaunchKernelGGL(k0_fused, dim3(K0_BLOCKS), dim3(256), 0, stream,
                       seg, off, s2, counter,
                       p1w0, p1b0, p1w1, p1b1, sorted_t, tabg);
    hipLaunchKernelGGL(k1_phi1, dim3(K1_BLOCKS), dim3(256), 0, stream,
                       values, off, sorted_t, tabg, ev);
    hipLaunchKernelGGL(k2_events, dim3(K2_BLOCKS), dim3(64), 0, stream,
                       ev, r1w0, r1b0, r1w1, r1b1, o1w, o1b,
                       p2w0, p2b0, p2w1, p2b1, s2, counter,
                       r2w0, r2b0, r2w1, r2b1, o2w, o2b, (float*)d_out);
}